// Round 9
// baseline (169.222 us; speedup 1.0000x reference)
//
#include <hip/hip_runtime.h>
#include <math.h>

// MPS-RNN 2D forward: L=8, M=8, DCUT=6, HL=2, N=64, B=32768
// Round-9 = round-8 with the staging bug fixed (all small-array staging now
// within 256 threads). 8 lanes/sample: g=sub&3 owns rows g*3..g*3+2 of the
// 12 (a,o) pairs; ch2=sub>>2 owns c-half {0..2}/{3..5} of the T contraction.
// T partials combined via shfl_xor(4). One snake-row (8 sites) of params in
// LDS at a time -> ~25KB/block -> 4 blocks/CU, 16 waves/CU.

#define MCOLS 8
#define DC    6
#define NQ    64
#define BT    256
#define SPB   32           // samples per block (8 lanes each)

// LDS float offsets for an 8-site (one snake row) chunk
#define TL     0           // 8*432 = 3456
#define MHL    3456        // 8*72  = 576
#define MVL    4032        // 8*72  = 576
#define VL     4608        // 8*12  = 96
#define WL     4704        // 8*6   = 48
#define EL     4752        // eta^2: 8*6 = 48
#define CL     4800        // 8
#define PARAM_F 4808
#define VSF    (48 * SPB)  // vertical state: [(j*6+o)*SPB + s]

__global__ __launch_bounds__(BT, 4) void mps_rnn9(
    const float* __restrict__ Mh,   // (L,M,2,6,6)
    const float* __restrict__ Mv,   // (L,M,2,6,6)
    const float* __restrict__ Vp,   // (L,M,2,6)
    const float* __restrict__ Tp,   // (L,M,2,6,6,6)
    const float* __restrict__ Wp,   // (L,M,6)
    const float* __restrict__ Cp,   // (L,M)
    const float* __restrict__ Ep,   // (L,M,6)
    const int*   __restrict__ X,    // (B,64)
    float*       __restrict__ out,
    int Bn, int writeImag)
{
    __shared__ float ps[PARAM_F];
    __shared__ float vs[VSF];

    const int t   = threadIdx.x;
    const int sub = t & 7;
    const int s   = t >> 3;
    int b = blockIdx.x * SPB + s;
    const bool valid = (b < Bn);
    if (!valid) b = Bn - 1;          // clamp loads; no early return (barriers!)

    const int g    = sub & 3;        // row group: rows g*3..g*3+2
    const int r0   = g * 3;
    const int mya  = g >> 1;
    const int ohi  = g & 1;
    const int c0   = (sub >> 2) * 3; // c-half base of T contraction
    const int lbase = (t & 63) & ~7;

    // cooperative bit pack: each lane 8 qubits, or-combine across octet
    unsigned long long bits;
    {
        const int4* xr = reinterpret_cast<const int4*>(X + (size_t)b * NQ + sub * 8);
        int4 v0 = xr[0], v1 = xr[1];
        unsigned part =  (unsigned)(v0.x & 1)       | ((unsigned)(v0.y & 1) << 1)
                      | ((unsigned)(v0.z & 1) << 2) | ((unsigned)(v0.w & 1) << 3)
                      | ((unsigned)(v1.x & 1) << 4) | ((unsigned)(v1.y & 1) << 5)
                      | ((unsigned)(v1.z & 1) << 6) | ((unsigned)(v1.w & 1) << 7);
        bits = (unsigned long long)part << (8 * sub);
        bits |= __shfl_xor(bits, 1, 64);
        bits |= __shfl_xor(bits, 2, 64);
        bits |= __shfl_xor(bits, 4, 64);
    }

    for (int u = t; u < VSF; u += BT) vs[u] = 0.f;

    float hh[6];
    float amp2 = 1.f, phi = 0.f;

    for (int ri = 0; ri < 8; ++ri) {
        __syncthreads();             // previous chunk fully consumed
        // ---- stage row ri: sites ri*8 .. ri*8+7 (natural column order)
        {
            const float4* gT = reinterpret_cast<const float4*>(Tp) + ri * 864;
            float4* lT = reinterpret_cast<float4*>(ps + TL);
            for (int u = t; u < 864; u += BT) lT[u] = gT[u];

            const float4* gMh = reinterpret_cast<const float4*>(Mh) + ri * 144;
            const float4* gMv = reinterpret_cast<const float4*>(Mv) + ri * 144;
            float4* lMh = reinterpret_cast<float4*>(ps + MHL);
            float4* lMv = reinterpret_cast<float4*>(ps + MVL);
            if (t < 144) lMh[t] = gMh[t];
            else         lMv[t - 144] = gMv[t - 144];          // first 112
            if (t < 32)  lMv[112 + t] = gMv[112 + t];          // last 32
            else if (t < 56) {
                int u = t - 32;                                 // 24: V
                reinterpret_cast<float4*>(ps + VL)[u] =
                    reinterpret_cast<const float4*>(Vp)[ri * 24 + u];
            } else if (t < 68) {
                int u = t - 56;                                 // 12: W
                reinterpret_cast<float4*>(ps + WL)[u] =
                    reinterpret_cast<const float4*>(Wp)[ri * 12 + u];
            } else if (t < 80) {
                int u = t - 68;                                 // 12: eta^2
                float4 e = reinterpret_cast<const float4*>(Ep)[ri * 12 + u];
                e.x *= e.x; e.y *= e.y; e.z *= e.z; e.w *= e.w;
                reinterpret_cast<float4*>(ps + EL)[u] = e;
            } else if (t < 82) {
                int u = t - 80;                                 // 2: C
                reinterpret_cast<float4*>(ps + CL)[u] =
                    reinterpret_cast<const float4*>(Cp)[ri * 2 + u];
            }
        }
        __syncthreads();             // chunk visible

        const int par = ri & 1;
        const unsigned cbr = (unsigned)(bits >> (ri * 8)) & 0xFFu;

        #pragma unroll 2
        for (int qq = 0; qq < 8; ++qq) {
            const int j = par ? 7 - qq : qq;     // snake column

            if (qq == 0) {                       // left boundary
                #pragma unroll
                for (int o = 0; o < 6; ++o) hh[o] = 1.f;
            }

            float hv[6];                         // vertical state (broadcast)
            #pragma unroll
            for (int o = 0; o < 6; ++o) hv[o] = vs[(j * 6 + o) * SPB + s];

            const float* Tb  = ps + TL  + j * 432 + r0 * 36 + c0 * 6;
            const float* Hb  = ps + MHL + j * 72 + r0 * 6;
            const float* Gb  = ps + MVL + j * 72 + r0 * 6;
            const float* vvb = ps + VL  + j * 12 + r0;
            const float* wb  = ps + WL  + j * 6;
            const float* eb  = ps + EL  + j * 6 + ohi * 3;
            const float ck   = ps[CL + j];

            const float hc0 = hh[c0], hc1 = hh[c0 + 1], hc2 = hh[c0 + 2];

            float accp[3], rest[3];
            #pragma unroll
            for (int lr = 0; lr < 3; ++lr) {
                // T partial over this lane's c-half (18 contiguous floats)
                float tf[18];
                #pragma unroll
                for (int p = 0; p < 9; ++p) {
                    float2 x = reinterpret_cast<const float2*>(Tb + lr * 36)[p];
                    tf[2*p] = x.x; tf[2*p+1] = x.y;
                }
                float s0 = fmaf(tf[0], hv[0], fmaf(tf[2], hv[2], tf[4]*hv[4]))
                         + fmaf(tf[1], hv[1], fmaf(tf[3], hv[3], tf[5]*hv[5]));
                float s1 = fmaf(tf[6], hv[0], fmaf(tf[8], hv[2], tf[10]*hv[4]))
                         + fmaf(tf[7], hv[1], fmaf(tf[9], hv[3], tf[11]*hv[5]));
                float s2 = fmaf(tf[12], hv[0], fmaf(tf[14], hv[2], tf[16]*hv[4]))
                         + fmaf(tf[13], hv[1], fmaf(tf[15], hv[3], tf[17]*hv[5]));
                accp[lr] = fmaf(s0, hc0, fmaf(s1, hc1, s2 * hc2));

                // rest (redundant in both halves): base + Mh.hh + Mv.hv
                float mh[6], mv[6];
                #pragma unroll
                for (int p = 0; p < 3; ++p) {
                    float2 a = reinterpret_cast<const float2*>(Hb + lr * 6)[p];
                    mh[2*p] = a.x; mh[2*p+1] = a.y;
                    float2 c = reinterpret_cast<const float2*>(Gb + lr * 6)[p];
                    mv[2*p] = c.x; mv[2*p+1] = c.y;
                }
                const float hho = ohi ? hh[lr + 3] : hh[lr];
                const float hvo = ohi ? hv[lr + 3] : hv[lr];
                float ra = fmaf(mh[0], hh[0], fmaf(mh[2], hh[2], mh[4]*hh[4]));
                float rb = fmaf(mh[1], hh[1], fmaf(mh[3], hh[3], mh[5]*hh[5]));
                float rc = fmaf(mv[0], hv[0], fmaf(mv[2], hv[2], mv[4]*hv[4]));
                float rd = fmaf(mv[1], hv[1], fmaf(mv[3], hv[3], mv[5]*hv[5]));
                rest[lr] = ((vvb[lr] + hho + hvo) + (ra + rb)) + (rc + rd);
            }

            // combine T halves (xor-4), then full acc
            float acc[3];
            #pragma unroll
            for (int lr = 0; lr < 3; ++lr)
                acc[lr] = rest[lr] + accp[lr] + __shfl_xor(accp[lr], 4, 64);

            // reductions over the 12 rows (replicated in both ch2 halves)
            float a2[3];
            #pragma unroll
            for (int lr = 0; lr < 3; ++lr) a2[lr] = acc[lr] * acc[lr];
            float ssl = (a2[0] + a2[1]) + a2[2];
            float pq  = fmaf(eb[0], a2[0], fmaf(eb[1], a2[1], eb[2] * a2[2]));
            ssl += __shfl_xor(ssl, 1, 64);
            pq  += __shfl_xor(pq,  1, 64);
            const float ssq = ssl + __shfl_xor(ssl, 2, 64);
            const float pqx = __shfl_xor(pq, 2, 64);
            const float inv = rsqrtf(ssq + 1e-12f);

            const int sel = (cbr >> qq) & 1;
            const float qsel = (mya == sel) ? pq : pqx;
            amp2 *= qsel / (pq + pqx);

            // rebuild h_sel from the ch2=0 lanes of the chosen a
            const int l0 = lbase + 2 * sel;
            const int l1 = l0 + 1;
            hh[0] = __shfl(acc[0], l0, 64) * inv;
            hh[1] = __shfl(acc[1], l0, 64) * inv;
            hh[2] = __shfl(acc[2], l0, 64) * inv;
            hh[3] = __shfl(acc[0], l1, 64) * inv;
            hh[4] = __shfl(acc[1], l1, 64) * inv;
            hh[5] = __shfl(acc[2], l1, 64) * inv;

            float ph = ck;
            #pragma unroll
            for (int o = 0; o < 6; ++o) ph = fmaf(wb[o], hh[o], ph);
            phi += ph;

            if (sub == 0) {
                #pragma unroll
                for (int o = 0; o < 6; ++o) vs[(j * 6 + o) * SPB + s] = hh[o];
            }
            __builtin_amdgcn_wave_barrier();   // keep vs write/read ordered
        }
    }

    if (sub == 0 && valid) {
        const float amp = sqrtf(amp2);
        if (writeImag) {
            out[2 * b + 0] = amp * cosf(phi);
            out[2 * b + 1] = amp * sinf(phi);
        } else {
            out[b] = amp * cosf(phi);
        }
    }
}

extern "C" void kernel_launch(void* const* d_in, const int* in_sizes, int n_in,
                              void* d_out, int out_size, void* d_ws, size_t ws_size,
                              hipStream_t stream) {
    const float* Mh = (const float*)d_in[0];
    const float* Mv = (const float*)d_in[1];
    const float* Vp = (const float*)d_in[2];
    const float* Tp = (const float*)d_in[3];
    const float* Wp = (const float*)d_in[4];
    const float* Cp = (const float*)d_in[5];
    const float* Ep = (const float*)d_in[6];
    const int*   X  = (const int*)d_in[7];
    float* out = (float*)d_out;

    const int Bn = in_sizes[7] / NQ;                 // 32768
    const int writeImag = (out_size >= 2 * Bn) ? 1 : 0;
    const int grid = (Bn + SPB - 1) / SPB;           // 1024 blocks of 256 threads

    mps_rnn9<<<grid, BT, 0, stream>>>(Mh, Mv, Vp, Tp, Wp, Cp, Ep, X, out,
                                      Bn, writeImag);
}

// Round 11
// 110.833 us; speedup vs baseline: 1.5268x; 1.5268x over previous
//
#include <hip/hip_runtime.h>
#include <hip/hip_fp16.h>
#include <math.h>

// MPS-RNN 2D forward: L=8, M=8, DCUT=6, HL=2, N=64, B=32768
// Round-11 = round-10 with the eta^2 staging bug fixed (fold into t<192
// branch; each thread writes its V element AND its eta^2 element).
// 4 lanes/sample, SPB=64, 16-site chunks. LDS-byte reduction:
//   - T staged fp16, rows padded to 80B -> 5 aligned b128 reads/row
//   - Mh/Mv repacked contiguous per (site,sub), b64 reads
//   - V + eta^2 packed per (site,sub) in one 32B block -> 2 reads
//   - W, C read from global with wave-uniform index -> scalar (SMEM) path
//   - vertical state [j][s][12] -> b128+b64 read, conflict-free

#define NQ  64
#define BT  256
#define SPB 64

#if defined(__has_builtin)
#  if __has_builtin(__builtin_amdgcn_rcpf)
#    define FAST_RCP(x) __builtin_amdgcn_rcpf(x)
#  else
#    define FAST_RCP(x) (1.0f / (x))
#  endif
#  if __has_builtin(__builtin_amdgcn_rsqf)
#    define FAST_RSQ(x) __builtin_amdgcn_rsqf(x)
#  else
#    define FAST_RSQ(x) rsqrtf(x)
#  endif
#else
#  define FAST_RCP(x) (1.0f / (x))
#  define FAST_RSQ(x) rsqrtf(x)
#endif

union U16x8 { uint4 u4; __half2 h2[4]; };
union U16x4 { uint2 u2; __half2 h2[2]; };

#define UNPACK8(W, o) \
    tf[(o)+0]=__low2float((W).h2[0]); tf[(o)+1]=__high2float((W).h2[0]); \
    tf[(o)+2]=__low2float((W).h2[1]); tf[(o)+3]=__high2float((W).h2[1]); \
    tf[(o)+4]=__low2float((W).h2[2]); tf[(o)+5]=__high2float((W).h2[2]); \
    tf[(o)+6]=__low2float((W).h2[3]); tf[(o)+7]=__high2float((W).h2[3]);

__global__ __launch_bounds__(BT, 1) void mps_rnn11(
    const float* __restrict__ Mh,   // (L,M,2,6,6)
    const float* __restrict__ Mv,   // (L,M,2,6,6)
    const float* __restrict__ Vp,   // (L,M,2,6)
    const float* __restrict__ Tp,   // (L,M,2,6,6,6)
    const float* __restrict__ Wp,   // (L,M,6)
    const float* __restrict__ Cp,   // (L,M)
    const float* __restrict__ Ep,   // (L,M,6)
    const int*   __restrict__ X,    // (B,64)
    float*       __restrict__ out,
    int Bn, int writeImag)
{
    __shared__ __half Tl[16 * 4 * 3 * 40];   // 15360 B, fp16 T (rows padded to 40 halves)
    __shared__ float  MHV[16 * 4 * 48];      // 12288 B (mh 3x(6+2) | mv 3x(6+2))
    __shared__ float  VE [16 * 4 * 8];       // 2048 B  (v0 v1 v2 e0^2 e1^2 e2^2 pad pad)
    __shared__ float  vsm[8 * 64 * 12];      // 24576 B vertical state [j][s][12]

    const int t   = threadIdx.x;
    const int sub = t & 3;
    const int s   = t >> 2;
    int b = blockIdx.x * SPB + s;
    const bool valid = (b < Bn);
    if (!valid) b = Bn - 1;          // clamp loads; no early return (barriers!)

    // cooperative bit pack (each lane 16 qubits, OR-combine across group)
    unsigned long long bits;
    {
        const int4* xr = reinterpret_cast<const int4*>(X + (size_t)b * NQ + sub * 16);
        unsigned long long part = 0ull;
        #pragma unroll
        for (int q = 0; q < 4; ++q) {
            int4 v = xr[q];
            part |= (unsigned long long)(v.x & 1) << (4 * q + 0);
            part |= (unsigned long long)(v.y & 1) << (4 * q + 1);
            part |= (unsigned long long)(v.z & 1) << (4 * q + 2);
            part |= (unsigned long long)(v.w & 1) << (4 * q + 3);
        }
        bits = part << (16 * sub);
        bits |= __shfl_xor(bits, 1, 64);
        bits |= __shfl_xor(bits, 2, 64);
    }

    for (int u = t; u < 8 * 64 * 12; u += BT) vsm[u] = 0.f;

    const int mya   = sub >> 1;
    const int ohi   = sub & 1;
    const int lbase = (t & 63) & ~3;

    float hh[6];
    float amp2 = 1.f, phi = 0.f;

    for (int ch = 0; ch < 4; ++ch) {
        __syncthreads();             // previous chunk fully consumed
        // ---- stage chunk ch (sites 16ch..16ch+15)
        {
            // T: fp32 pairs -> fp16 pairs, row-padded layout
            const float2* gT = reinterpret_cast<const float2*>(Tp + ch * 6912);
            for (int p = t; p < 3456; p += BT) {
                int gi = 2 * p;
                int site = gi / 432, rr = gi - site * 432;
                int sb = rr / 108,  r2 = rr - sb * 108;
                int lr = r2 / 36,   w  = r2 - lr * 36;
                float2 v = gT[p];
                *reinterpret_cast<__half2*>(
                    &Tl[(site * 12 + sb * 3 + lr) * 40 + w]) =
                    __floats2half2_rn(v.x, v.y);
            }
            // Mh/Mv: contiguous per (site,sub), rows padded to 8 floats
            const float2* gH = reinterpret_cast<const float2*>(Mh + ch * 1152);
            const float2* gV = reinterpret_cast<const float2*>(Mv + ch * 1152);
            for (int p = t; p < 576; p += BT) {
                int gi = 2 * p;
                int site = gi / 72, rr = gi - site * 72;
                int sb = rr / 18,   r2 = rr - sb * 18;
                int row = r2 / 6,   pp = r2 - row * 6;
                int base = (site * 4 + sb) * 48 + row * 8 + pp;
                *reinterpret_cast<float2*>(&MHV[base])      = gH[p];
                *reinterpret_cast<float2*>(&MHV[base + 24]) = gV[p];
            }
            // V + eta^2 packed (FIX: both from the same t<192 branch)
            if (t < 192) {
                int site = t / 12, q = t - site * 12;
                int sb = q / 3,    c = q - sb * 3;
                VE[(site * 4 + sb) * 8 + c] = Vp[ch * 192 + t];
                float e = Ep[ch * 96 + site * 6 + (sb & 1) * 3 + c];
                VE[(site * 4 + sb) * 8 + 3 + c] = e * e;
            }
        }
        __syncthreads();             // chunk visible

        #pragma unroll
        for (int ih = 0; ih < 2; ++ih) {
            const unsigned cbr = (unsigned)(bits >> (ch * 16 + ih * 8)) & 0xFFu;

            #pragma unroll 2
            for (int qq = 0; qq < 8; ++qq) {
                const int j    = ih ? 7 - qq : qq;      // snake column
                const int slot = ih * 8 + j;
                const int siteg = ch * 16 + slot;

                const __half* Tb  = Tl  + (slot * 12 + sub * 3) * 40;
                const float*  Mb  = MHV + (slot * 4 + sub) * 48;
                const float*  VEb = VE  + (slot * 4 + sub) * 8;
                const float*  wq  = Wp + siteg * 6;     // uniform -> scalar path
                const float   ck  = Cp[siteg];          // uniform -> scalar path

                if (qq == 0) {                          // left boundary
                    #pragma unroll
                    for (int o = 0; o < 6; ++o) hh[o] = 1.f;
                }

                float hv[6];
                {
                    const float* vrow = vsm + j * 768 + s * 12;
                    float4 h03 = *reinterpret_cast<const float4*>(vrow);
                    float2 h45 = *reinterpret_cast<const float2*>(vrow + 4);
                    hv[0]=h03.x; hv[1]=h03.y; hv[2]=h03.z; hv[3]=h03.w;
                    hv[4]=h45.x; hv[5]=h45.y;
                }

                float4 ve0 = *reinterpret_cast<const float4*>(VEb);     // v0 v1 v2 e0
                float2 ve1 = *reinterpret_cast<const float2*>(VEb + 4); // e1 e2
                const float vv[3] = { ve0.x, ve0.y, ve0.z };
                const float e2[3] = { ve0.w, ve1.x, ve1.y };

                float acc[3];
                #pragma unroll
                for (int lr = 0; lr < 3; ++lr) {
                    const __half* Tr = Tb + lr * 40;
                    U16x8 w0, w1, w2, w3; U16x4 w4;
                    w0.u4 = *reinterpret_cast<const uint4*>(Tr);
                    w1.u4 = *reinterpret_cast<const uint4*>(Tr + 8);
                    w2.u4 = *reinterpret_cast<const uint4*>(Tr + 16);
                    w3.u4 = *reinterpret_cast<const uint4*>(Tr + 24);
                    w4.u2 = *reinterpret_cast<const uint2*>(Tr + 32);
                    float tf[36];
                    UNPACK8(w0, 0) UNPACK8(w1, 8) UNPACK8(w2, 16) UNPACK8(w3, 24)
                    tf[32]=__low2float(w4.h2[0]); tf[33]=__high2float(w4.h2[0]);
                    tf[34]=__low2float(w4.h2[1]); tf[35]=__high2float(w4.h2[1]);

                    float2 a0 = *reinterpret_cast<const float2*>(Mb + lr * 8);
                    float2 a1 = *reinterpret_cast<const float2*>(Mb + lr * 8 + 2);
                    float2 a2 = *reinterpret_cast<const float2*>(Mb + lr * 8 + 4);
                    float2 c0 = *reinterpret_cast<const float2*>(Mb + 24 + lr * 8);
                    float2 c1 = *reinterpret_cast<const float2*>(Mb + 24 + lr * 8 + 2);
                    float2 c2 = *reinterpret_cast<const float2*>(Mb + 24 + lr * 8 + 4);

                    const float hho = ohi ? hh[lr + 3] : hh[lr];
                    const float hvo = ohi ? hv[lr + 3] : hv[lr];
                    const float base = vv[lr] + hho + hvo;

                    float sc6[6];
                    #pragma unroll
                    for (int c = 0; c < 6; ++c) {
                        const int o0 = c * 6;
                        float sa = fmaf(tf[o0+0], hv[0], fmaf(tf[o0+2], hv[2], tf[o0+4]*hv[4]));
                        float sb = fmaf(tf[o0+1], hv[1], fmaf(tf[o0+3], hv[3], tf[o0+5]*hv[5]));
                        sc6[c] = sa + sb;
                    }
                    float p0 = fmaf(sc6[0], hh[0], fmaf(sc6[3], hh[3], base));
                    float p1 = fmaf(sc6[1], hh[1], sc6[4] * hh[4]);
                    float p2 = fmaf(sc6[2], hh[2], sc6[5] * hh[5]);
                    float ma = fmaf(a0.x, hh[0], fmaf(a1.x, hh[2], a2.x*hh[4]));
                    float mb = fmaf(a0.y, hh[1], fmaf(a1.y, hh[3], a2.y*hh[5]));
                    float na = fmaf(c0.x, hv[0], fmaf(c1.x, hv[2], c2.x*hv[4]));
                    float nb = fmaf(c0.y, hv[1], fmaf(c1.y, hv[3], c2.y*hv[5]));
                    acc[lr] = ((p0 + p1) + (p2 + ma)) + ((mb + na) + nb);
                }

                // 4-lane reductions on unnormalized acc (inv^2 cancels in prob)
                float a2_[3];
                #pragma unroll
                for (int lr = 0; lr < 3; ++lr) a2_[lr] = acc[lr] * acc[lr];
                float ssl = (a2_[0] + a2_[1]) + a2_[2];
                float pq  = fmaf(e2[0], a2_[0], fmaf(e2[1], a2_[1], e2[2] * a2_[2]));
                ssl += __shfl_xor(ssl, 1, 64);
                pq  += __shfl_xor(pq,  1, 64);
                const float ssq = ssl + __shfl_xor(ssl, 2, 64);
                const float pqx = __shfl_xor(pq, 2, 64);
                const float inv = FAST_RSQ(ssq + 1e-12f);

                const int sel = (cbr >> qq) & 1;
                const float qsel = (mya == sel) ? pq : pqx;
                amp2 *= qsel * FAST_RCP(pq + pqx);

                // rebuild h_sel: shfl unnormalized acc, scale by inv
                const int l0 = lbase + 2 * sel;
                const int l1 = l0 + 1;
                hh[0] = __shfl(acc[0], l0, 64) * inv;
                hh[1] = __shfl(acc[1], l0, 64) * inv;
                hh[2] = __shfl(acc[2], l0, 64) * inv;
                hh[3] = __shfl(acc[0], l1, 64) * inv;
                hh[4] = __shfl(acc[1], l1, 64) * inv;
                hh[5] = __shfl(acc[2], l1, 64) * inv;

                float ph = ck;
                #pragma unroll
                for (int o = 0; o < 6; ++o) ph = fmaf(wq[o], hh[o], ph);
                phi += ph;

                if (sub == 0) {
                    float* vrow = vsm + j * 768 + s * 12;
                    *reinterpret_cast<float4*>(vrow) =
                        make_float4(hh[0], hh[1], hh[2], hh[3]);
                    *reinterpret_cast<float2*>(vrow + 4) =
                        make_float2(hh[4], hh[5]);
                }
            }
        }
    }

    if (sub == 0 && valid) {
        const float amp = sqrtf(amp2);
        if (writeImag) {
            out[2 * b + 0] = amp * cosf(phi);
            out[2 * b + 1] = amp * sinf(phi);
        } else {
            out[b] = amp * cosf(phi);
        }
    }
}

extern "C" void kernel_launch(void* const* d_in, const int* in_sizes, int n_in,
                              void* d_out, int out_size, void* d_ws, size_t ws_size,
                              hipStream_t stream) {
    const float* Mh = (const float*)d_in[0];
    const float* Mv = (const float*)d_in[1];
    const float* Vp = (const float*)d_in[2];
    const float* Tp = (const float*)d_in[3];
    const float* Wp = (const float*)d_in[4];
    const float* Cp = (const float*)d_in[5];
    const float* Ep = (const float*)d_in[6];
    const int*   X  = (const int*)d_in[7];
    float* out = (float*)d_out;

    const int Bn = in_sizes[7] / NQ;                 // 32768
    const int writeImag = (out_size >= 2 * Bn) ? 1 : 0;
    const int grid = (Bn + SPB - 1) / SPB;           // 512 blocks of 256 threads

    mps_rnn11<<<grid, BT, 0, stream>>>(Mh, Mv, Vp, Tp, Wp, Cp, Ep, X, out,
                                       Bn, writeImag);
}

// Round 13
// 83.145 us; speedup vs baseline: 2.0353x; 1.3330x over previous
//
#include <hip/hip_runtime.h>
#include <hip/hip_fp16.h>
#include <math.h>

// MPS-RNN 2D forward: L=8, M=8, DCUT=6, HL=2, N=64, B=32768
// Round-13 = round-12 with the cvt_pkrtz/fdot2 type mismatch fixed via a
// bit-copy helper. (a) T contraction via v_dot2_f32_f16; (b) all cross-lane
// ops via DPP quad_perm instead of ds_bpermute.

#define NQ  64
#define BT  256
#define SPB 64

typedef _Float16 h2v __attribute__((ext_vector_type(2)));
typedef __fp16  p2v __attribute__((ext_vector_type(2)));
union H2U { unsigned u; h2v h; __half2 hh; };

static __device__ __forceinline__ h2v pack2(float a, float b) {
    p2v p = __builtin_amdgcn_cvt_pkrtz(a, b);
    h2v r; __builtin_memcpy(&r, &p, sizeof(r));
    return r;
}

#define DPPF(x, ctrl) __int_as_float(__builtin_amdgcn_update_dpp(            \
    __float_as_int(x), __float_as_int(x), (ctrl), 0xF, 0xF, false))
#define QP_XOR1 0xB1   // quad_perm [1,0,3,2]
#define QP_XOR2 0x4E   // quad_perm [2,3,0,1]
#define QP_BC0  0x00   // quad_perm [0,0,0,0]
#define QP_BC1  0x55   // [1,1,1,1]
#define QP_BC2  0xAA   // [2,2,2,2]
#define QP_BC3  0xFF   // [3,3,3,3]

#if defined(__has_builtin)
#  if __has_builtin(__builtin_amdgcn_rcpf)
#    define FAST_RCP(x) __builtin_amdgcn_rcpf(x)
#  else
#    define FAST_RCP(x) (1.0f / (x))
#  endif
#  if __has_builtin(__builtin_amdgcn_rsqf)
#    define FAST_RSQ(x) __builtin_amdgcn_rsqf(x)
#  else
#    define FAST_RSQ(x) rsqrtf(x)
#  endif
#  if __has_builtin(__builtin_amdgcn_fdot2)
#    define HAS_FDOT2 1
#  endif
#else
#  define FAST_RCP(x) (1.0f / (x))
#  define FAST_RSQ(x) rsqrtf(x)
#endif

static __device__ __forceinline__ float fdot2u(unsigned a, h2v b, float c) {
#ifdef HAS_FDOT2
    H2U u; u.u = a;
    return __builtin_amdgcn_fdot2(u.h, b, c, false);
#else
    H2U u; u.u = a;
    return fmaf((float)u.h.x, (float)b.x, fmaf((float)u.h.y, (float)b.y, c));
#endif
}

__global__ __launch_bounds__(BT, 1) void mps_rnn13(
    const float* __restrict__ Mh,   // (L,M,2,6,6)
    const float* __restrict__ Mv,   // (L,M,2,6,6)
    const float* __restrict__ Vp,   // (L,M,2,6)
    const float* __restrict__ Tp,   // (L,M,2,6,6,6)
    const float* __restrict__ Wp,   // (L,M,6)
    const float* __restrict__ Cp,   // (L,M)
    const float* __restrict__ Ep,   // (L,M,6)
    const int*   __restrict__ X,    // (B,64)
    float*       __restrict__ out,
    int Bn, int writeImag)
{
    __shared__ unsigned Tl[16 * 12 * 20];    // 15360 B: fp16 T, rows of 18 half2 + pad
    __shared__ float    MHV[16 * 4 * 48];    // 12288 B (mh 3x(6+2) | mv 3x(6+2)), fp32
    __shared__ float    VE [16 * 4 * 8];     // 2048 B  (v0 v1 v2 e0^2 e1^2 e2^2 pad pad)
    __shared__ float    vsm[8 * 64 * 12];    // 24576 B vertical state [j][s][12]

    const int t   = threadIdx.x;
    const int sub = t & 3;
    const int s   = t >> 2;
    int b = blockIdx.x * SPB + s;
    const bool valid = (b < Bn);
    if (!valid) b = Bn - 1;          // clamp loads; no early return (barriers!)

    // cooperative bit pack (each lane 16 qubits, OR-combine across group)
    unsigned long long bits;
    {
        const int4* xr = reinterpret_cast<const int4*>(X + (size_t)b * NQ + sub * 16);
        unsigned long long part = 0ull;
        #pragma unroll
        for (int q = 0; q < 4; ++q) {
            int4 v = xr[q];
            part |= (unsigned long long)(v.x & 1) << (4 * q + 0);
            part |= (unsigned long long)(v.y & 1) << (4 * q + 1);
            part |= (unsigned long long)(v.z & 1) << (4 * q + 2);
            part |= (unsigned long long)(v.w & 1) << (4 * q + 3);
        }
        bits = part << (16 * sub);
        bits |= __shfl_xor(bits, 1, 64);
        bits |= __shfl_xor(bits, 2, 64);
    }

    for (int u = t; u < 8 * 64 * 12; u += BT) vsm[u] = 0.f;

    const int mya = sub >> 1;
    const int ohi = sub & 1;

    float hh[6];
    float amp2 = 1.f, phi = 0.f;

    for (int ch = 0; ch < 4; ++ch) {
        __syncthreads();             // previous chunk fully consumed
        // ---- stage chunk ch (sites 16ch..16ch+15)
        {
            // T: fp32 pairs -> fp16 half2 (RN), row-padded layout (20 uints/row)
            const float2* gT = reinterpret_cast<const float2*>(Tp + ch * 6912);
            for (int p = t; p < 3456; p += BT) {
                int gi = 2 * p;
                int site = gi / 432, rr = gi - site * 432;
                int sb = rr / 108,  r2 = rr - sb * 108;
                int lr = r2 / 36,   w  = r2 - lr * 36;
                float2 v = gT[p];
                H2U hu; hu.hh = __floats2half2_rn(v.x, v.y);
                Tl[(site * 12 + sb * 3 + lr) * 20 + (w >> 1)] = hu.u;
            }
            // Mh/Mv: fp32, contiguous per (site,sub), rows padded to 8 floats
            const float2* gH = reinterpret_cast<const float2*>(Mh + ch * 1152);
            const float2* gV = reinterpret_cast<const float2*>(Mv + ch * 1152);
            for (int p = t; p < 576; p += BT) {
                int gi = 2 * p;
                int site = gi / 72, rr = gi - site * 72;
                int sb = rr / 18,   r2 = rr - sb * 18;
                int row = r2 / 6,   pp = r2 - row * 6;
                int base = (site * 4 + sb) * 48 + row * 8 + pp;
                *reinterpret_cast<float2*>(&MHV[base])      = gH[p];
                *reinterpret_cast<float2*>(&MHV[base + 24]) = gV[p];
            }
            // V + eta^2 packed
            if (t < 192) {
                int site = t / 12, q = t - site * 12;
                int sb = q / 3,    c = q - sb * 3;
                VE[(site * 4 + sb) * 8 + c] = Vp[ch * 192 + t];
                float e = Ep[ch * 96 + site * 6 + (sb & 1) * 3 + c];
                VE[(site * 4 + sb) * 8 + 3 + c] = e * e;
            }
        }
        __syncthreads();             // chunk visible

        #pragma unroll
        for (int ih = 0; ih < 2; ++ih) {
            const unsigned cbr = (unsigned)(bits >> (ch * 16 + ih * 8)) & 0xFFu;

            #pragma unroll 2
            for (int qq = 0; qq < 8; ++qq) {
                const int j    = ih ? 7 - qq : qq;      // snake column
                const int slot = ih * 8 + j;
                const int siteg = ch * 16 + slot;

                const unsigned* Tb = Tl  + (slot * 12 + sub * 3) * 20;
                const float*    Mb = MHV + (slot * 4 + sub) * 48;
                const float*   VEb = VE  + (slot * 4 + sub) * 8;
                const float*    wq = Wp + siteg * 6;    // uniform -> scalar path
                const float     ck = Cp[siteg];         // uniform -> scalar path

                if (qq == 0) {                          // left boundary
                    #pragma unroll
                    for (int o = 0; o < 6; ++o) hh[o] = 1.f;
                }

                float hv[6];
                {
                    const float* vrow = vsm + j * 768 + s * 12;
                    float4 h03 = *reinterpret_cast<const float4*>(vrow);
                    float2 h45 = *reinterpret_cast<const float2*>(vrow + 4);
                    hv[0]=h03.x; hv[1]=h03.y; hv[2]=h03.z; hv[3]=h03.w;
                    hv[4]=h45.x; hv[5]=h45.y;
                }
                // hv packed once per step for the T dot2s
                const h2v hvh0 = pack2(hv[0], hv[1]);
                const h2v hvh1 = pack2(hv[2], hv[3]);
                const h2v hvh2 = pack2(hv[4], hv[5]);

                float4 ve0 = *reinterpret_cast<const float4*>(VEb);     // v0 v1 v2 e0
                float2 ve1 = *reinterpret_cast<const float2*>(VEb + 4); // e1 e2
                const float vv[3] = { ve0.x, ve0.y, ve0.z };
                const float e2[3] = { ve0.w, ve1.x, ve1.y };

                float acc[3];
                #pragma unroll
                for (int lr = 0; lr < 3; ++lr) {
                    const unsigned* Tr = Tb + lr * 20;
                    uint4 tA = *reinterpret_cast<const uint4*>(Tr);
                    uint4 tB = *reinterpret_cast<const uint4*>(Tr + 4);
                    uint4 tC = *reinterpret_cast<const uint4*>(Tr + 8);
                    uint4 tD = *reinterpret_cast<const uint4*>(Tr + 12);
                    uint2 tE = *reinterpret_cast<const uint2*>(Tr + 16);
                    const unsigned tw[18] = {tA.x,tA.y,tA.z,tA.w, tB.x,tB.y,tB.z,tB.w,
                                             tC.x,tC.y,tC.z,tC.w, tD.x,tD.y,tD.z,tD.w,
                                             tE.x,tE.y};
                    float sc[6];
                    #pragma unroll
                    for (int c = 0; c < 6; ++c)
                        sc[c] = fdot2u(tw[c*3+0], hvh0,
                                fdot2u(tw[c*3+1], hvh1,
                                fdot2u(tw[c*3+2], hvh2, 0.f)));

                    float2 a0 = *reinterpret_cast<const float2*>(Mb + lr * 8);
                    float2 a1 = *reinterpret_cast<const float2*>(Mb + lr * 8 + 2);
                    float2 a2 = *reinterpret_cast<const float2*>(Mb + lr * 8 + 4);
                    float2 c0 = *reinterpret_cast<const float2*>(Mb + 24 + lr * 8);
                    float2 c1 = *reinterpret_cast<const float2*>(Mb + 24 + lr * 8 + 2);
                    float2 c2 = *reinterpret_cast<const float2*>(Mb + 24 + lr * 8 + 4);

                    const float hho = ohi ? hh[lr + 3] : hh[lr];
                    const float hvo = ohi ? hv[lr + 3] : hv[lr];
                    const float base = vv[lr] + hho + hvo;

                    float ta = fmaf(sc[0], hh[0], fmaf(sc[2], hh[2], sc[4]*hh[4]));
                    float tb = fmaf(sc[1], hh[1], fmaf(sc[3], hh[3], sc[5]*hh[5]));
                    float ma = fmaf(a0.x, hh[0], fmaf(a1.x, hh[2], a2.x*hh[4]));
                    float mb = fmaf(a0.y, hh[1], fmaf(a1.y, hh[3], a2.y*hh[5]));
                    float na = fmaf(c0.x, hv[0], fmaf(c1.x, hv[2], c2.x*hv[4]));
                    float nb = fmaf(c0.y, hv[1], fmaf(c1.y, hv[3], c2.y*hv[5]));
                    acc[lr] = ((base + ta) + (tb + ma)) + ((mb + na) + nb);
                }

                // 4-lane reductions via DPP quad_perm (pure VALU, no LDS)
                float a2_[3];
                #pragma unroll
                for (int lr = 0; lr < 3; ++lr) a2_[lr] = acc[lr] * acc[lr];
                float ssl = (a2_[0] + a2_[1]) + a2_[2];
                float pq  = fmaf(e2[0], a2_[0], fmaf(e2[1], a2_[1], e2[2] * a2_[2]));
                float s1  = ssl + DPPF(ssl, QP_XOR1);
                float ssq = s1 + DPPF(s1, QP_XOR2);
                float p1  = pq + DPPF(pq, QP_XOR1);
                float px  = DPPF(p1, QP_XOR2);
                const float inv = FAST_RSQ(ssq + 1e-12f);

                const int sel = (cbr >> qq) & 1;
                const float qsel = (mya == sel) ? p1 : px;
                amp2 *= qsel * FAST_RCP(p1 + px);

                // rebuild h_sel via static quad-broadcasts + cndmask
                #pragma unroll
                for (int k = 0; k < 3; ++k) {
                    float b0 = DPPF(acc[k], QP_BC0);
                    float b1 = DPPF(acc[k], QP_BC1);
                    float b2 = DPPF(acc[k], QP_BC2);
                    float b3 = DPPF(acc[k], QP_BC3);
                    hh[k]     = (sel ? b2 : b0) * inv;
                    hh[k + 3] = (sel ? b3 : b1) * inv;
                }

                float ph = ck;
                #pragma unroll
                for (int o = 0; o < 6; ++o) ph = fmaf(wq[o], hh[o], ph);
                phi += ph;

                if (sub == 0) {
                    float* vrow = vsm + j * 768 + s * 12;
                    *reinterpret_cast<float4*>(vrow) =
                        make_float4(hh[0], hh[1], hh[2], hh[3]);
                    *reinterpret_cast<float2*>(vrow + 4) =
                        make_float2(hh[4], hh[5]);
                }
            }
        }
    }

    if (sub == 0 && valid) {
        const float amp = sqrtf(amp2);
        if (writeImag) {
            out[2 * b + 0] = amp * cosf(phi);
            out[2 * b + 1] = amp * sinf(phi);
        } else {
            out[b] = amp * cosf(phi);
        }
    }
}

extern "C" void kernel_launch(void* const* d_in, const int* in_sizes, int n_in,
                              void* d_out, int out_size, void* d_ws, size_t ws_size,
                              hipStream_t stream) {
    const float* Mh = (const float*)d_in[0];
    const float* Mv = (const float*)d_in[1];
    const float* Vp = (const float*)d_in[2];
    const float* Tp = (const float*)d_in[3];
    const float* Wp = (const float*)d_in[4];
    const float* Cp = (const float*)d_in[5];
    const float* Ep = (const float*)d_in[6];
    const int*   X  = (const int*)d_in[7];
    float* out = (float*)d_out;

    const int Bn = in_sizes[7] / NQ;                 // 32768
    const int writeImag = (out_size >= 2 * Bn) ? 1 : 0;
    const int grid = (Bn + SPB - 1) / SPB;           // 512 blocks of 256 threads

    mps_rnn13<<<grid, BT, 0, stream>>>(Mh, Mv, Vp, Tp, Wp, Cp, Ep, X, out,
                                       Bn, writeImag);
}

// Round 14
// 72.019 us; speedup vs baseline: 2.3497x; 1.1545x over previous
//
#include <hip/hip_runtime.h>
#include <hip/hip_fp16.h>
#include <math.h>

// MPS-RNN 2D forward: L=8, M=8, DCUT=6, HL=2, N=64, B=32768
// Round-14 = round-13 + full fp16/dot2 conversion:
//   - Mh/Mv also fp16, merged into the T row: one 96B row per (site, a*6+o)
//     = {18 T h2-pairs | 3 mh pairs | 3 mv pairs} -> 6x b128 reads/row
//   - normalize acc before DPP broadcast (3 muls instead of 6)
//   - phase accumulation tree (depth 3)
// Cross-lane all-DPP; V/eta^2/W/C/norm/prob fp32.

#define NQ  64
#define BT  256
#define SPB 64

typedef _Float16 h2v __attribute__((ext_vector_type(2)));
typedef __fp16  p2v __attribute__((ext_vector_type(2)));
union H2U { unsigned u; h2v h; __half2 hh; };

static __device__ __forceinline__ h2v pack2(float a, float b) {
    p2v p = __builtin_amdgcn_cvt_pkrtz(a, b);
    h2v r; __builtin_memcpy(&r, &p, sizeof(r));
    return r;
}

#define DPPF(x, ctrl) __int_as_float(__builtin_amdgcn_update_dpp(            \
    __float_as_int(x), __float_as_int(x), (ctrl), 0xF, 0xF, false))
#define QP_XOR1 0xB1   // quad_perm [1,0,3,2]
#define QP_XOR2 0x4E   // quad_perm [2,3,0,1]
#define QP_BC0  0x00
#define QP_BC1  0x55
#define QP_BC2  0xAA
#define QP_BC3  0xFF

#if defined(__has_builtin)
#  if __has_builtin(__builtin_amdgcn_rcpf)
#    define FAST_RCP(x) __builtin_amdgcn_rcpf(x)
#  else
#    define FAST_RCP(x) (1.0f / (x))
#  endif
#  if __has_builtin(__builtin_amdgcn_rsqf)
#    define FAST_RSQ(x) __builtin_amdgcn_rsqf(x)
#  else
#    define FAST_RSQ(x) rsqrtf(x)
#  endif
#  if __has_builtin(__builtin_amdgcn_fdot2)
#    define HAS_FDOT2 1
#  endif
#else
#  define FAST_RCP(x) (1.0f / (x))
#  define FAST_RSQ(x) rsqrtf(x)
#endif

static __device__ __forceinline__ float fdot2u(unsigned a, h2v b, float c) {
#ifdef HAS_FDOT2
    H2U u; u.u = a;
    return __builtin_amdgcn_fdot2(u.h, b, c, false);
#else
    H2U u; u.u = a;
    return fmaf((float)u.h.x, (float)b.x, fmaf((float)u.h.y, (float)b.y, c));
#endif
}

__global__ __launch_bounds__(BT, 1) void mps_rnn14(
    const float* __restrict__ Mh,   // (L,M,2,6,6)
    const float* __restrict__ Mv,   // (L,M,2,6,6)
    const float* __restrict__ Vp,   // (L,M,2,6)
    const float* __restrict__ Tp,   // (L,M,2,6,6,6)
    const float* __restrict__ Wp,   // (L,M,6)
    const float* __restrict__ Cp,   // (L,M)
    const float* __restrict__ Ep,   // (L,M,6)
    const int*   __restrict__ X,    // (B,64)
    float*       __restrict__ out,
    int Bn, int writeImag)
{
    // merged fp16 rows: [site][row(=a*6+o)][24 uints]: 18 T | 3 mh | 3 mv
    __shared__ unsigned Tl[16 * 12 * 24];    // 18432 B
    __shared__ float    VE [16 * 4 * 8];     // 2048 B (v0 v1 v2 e0^2 e1^2 e2^2 . .)
    __shared__ float    vsm[8 * 64 * 12];    // 24576 B vertical state [j][s][12]

    const int t   = threadIdx.x;
    const int sub = t & 3;
    const int s   = t >> 2;
    int b = blockIdx.x * SPB + s;
    const bool valid = (b < Bn);
    if (!valid) b = Bn - 1;          // clamp loads; no early return (barriers!)

    // cooperative bit pack (each lane 16 qubits, OR-combine across group)
    unsigned long long bits;
    {
        const int4* xr = reinterpret_cast<const int4*>(X + (size_t)b * NQ + sub * 16);
        unsigned long long part = 0ull;
        #pragma unroll
        for (int q = 0; q < 4; ++q) {
            int4 v = xr[q];
            part |= (unsigned long long)(v.x & 1) << (4 * q + 0);
            part |= (unsigned long long)(v.y & 1) << (4 * q + 1);
            part |= (unsigned long long)(v.z & 1) << (4 * q + 2);
            part |= (unsigned long long)(v.w & 1) << (4 * q + 3);
        }
        bits = part << (16 * sub);
        bits |= __shfl_xor(bits, 1, 64);
        bits |= __shfl_xor(bits, 2, 64);
    }

    for (int u = t; u < 8 * 64 * 12; u += BT) vsm[u] = 0.f;

    const int mya = sub >> 1;
    const int ohi = sub & 1;

    float hh[6];
    float amp2 = 1.f, phi = 0.f;

    for (int ch = 0; ch < 4; ++ch) {
        __syncthreads();             // previous chunk fully consumed
        // ---- stage chunk ch (sites 16ch..16ch+15)
        {
            // T: 216 fp32-pairs/site -> h2, row = pair/18, w = pair%18
            const float2* gT = reinterpret_cast<const float2*>(Tp + ch * 6912);
            for (int p = t; p < 3456; p += BT) {
                int site = p / 216, rr = p - site * 216;
                int row = rr / 18,  w  = rr - row * 18;
                float2 v = gT[p];
                H2U hu; hu.hh = __floats2half2_rn(v.x, v.y);
                Tl[(site * 12 + row) * 24 + w] = hu.u;
            }
            // Mh/Mv: 36 pairs/site each, row = rr/3, w = rr%3
            const float2* gH = reinterpret_cast<const float2*>(Mh + ch * 1152);
            const float2* gV = reinterpret_cast<const float2*>(Mv + ch * 1152);
            for (int p = t; p < 576; p += BT) {
                int site = p / 36, rr = p - site * 36;
                int row = rr / 3,  w  = rr - row * 3;
                float2 vh = gH[p], vv_ = gV[p];
                H2U a; a.hh = __floats2half2_rn(vh.x, vh.y);
                H2U c; c.hh = __floats2half2_rn(vv_.x, vv_.y);
                Tl[(site * 12 + row) * 24 + 18 + w] = a.u;
                Tl[(site * 12 + row) * 24 + 21 + w] = c.u;
            }
            // V + eta^2 packed (fp32)
            if (t < 192) {
                int site = t / 12, q = t - site * 12;
                int sb = q / 3,    c = q - sb * 3;
                VE[(site * 4 + sb) * 8 + c] = Vp[ch * 192 + t];
                float e = Ep[ch * 96 + site * 6 + (sb & 1) * 3 + c];
                VE[(site * 4 + sb) * 8 + 3 + c] = e * e;
            }
        }
        __syncthreads();             // chunk visible

        #pragma unroll
        for (int ih = 0; ih < 2; ++ih) {
            const unsigned cbr = (unsigned)(bits >> (ch * 16 + ih * 8)) & 0xFFu;

            #pragma unroll 2
            for (int qq = 0; qq < 8; ++qq) {
                const int j    = ih ? 7 - qq : qq;      // snake column
                const int slot = ih * 8 + j;
                const int siteg = ch * 16 + slot;

                const unsigned* Tb = Tl + (slot * 12 + sub * 3) * 24;
                const float*   VEb = VE + (slot * 4 + sub) * 8;
                const float*    wq = Wp + siteg * 6;    // uniform -> scalar path
                const float     ck = Cp[siteg];         // uniform -> scalar path

                if (qq == 0) {                          // left boundary
                    #pragma unroll
                    for (int o = 0; o < 6; ++o) hh[o] = 1.f;
                }

                float hv[6];
                {
                    const float* vrow = vsm + j * 768 + s * 12;
                    float4 h03 = *reinterpret_cast<const float4*>(vrow);
                    float2 h45 = *reinterpret_cast<const float2*>(vrow + 4);
                    hv[0]=h03.x; hv[1]=h03.y; hv[2]=h03.z; hv[3]=h03.w;
                    hv[4]=h45.x; hv[5]=h45.y;
                }
                const h2v hvh0 = pack2(hv[0], hv[1]);
                const h2v hvh1 = pack2(hv[2], hv[3]);
                const h2v hvh2 = pack2(hv[4], hv[5]);
                const h2v hhp0 = pack2(hh[0], hh[1]);
                const h2v hhp1 = pack2(hh[2], hh[3]);
                const h2v hhp2 = pack2(hh[4], hh[5]);

                float4 ve0 = *reinterpret_cast<const float4*>(VEb);     // v0 v1 v2 e0
                float2 ve1 = *reinterpret_cast<const float2*>(VEb + 4); // e1 e2
                const float vv[3] = { ve0.x, ve0.y, ve0.z };
                const float e2[3] = { ve0.w, ve1.x, ve1.y };

                float acc[3];
                #pragma unroll
                for (int lr = 0; lr < 3; ++lr) {
                    const unsigned* Tr = Tb + lr * 24;
                    uint4 tA = *reinterpret_cast<const uint4*>(Tr);      // T 0..3
                    uint4 tB = *reinterpret_cast<const uint4*>(Tr + 4);  // T 4..7
                    uint4 tC = *reinterpret_cast<const uint4*>(Tr + 8);  // T 8..11
                    uint4 tD = *reinterpret_cast<const uint4*>(Tr + 12); // T 12..15
                    uint4 tE = *reinterpret_cast<const uint4*>(Tr + 16); // T16 T17 mh0 mh1
                    uint4 tF = *reinterpret_cast<const uint4*>(Tr + 20); // mh2 mv0 mv1 mv2
                    const unsigned tw[18] = {tA.x,tA.y,tA.z,tA.w, tB.x,tB.y,tB.z,tB.w,
                                             tC.x,tC.y,tC.z,tC.w, tD.x,tD.y,tD.z,tD.w,
                                             tE.x,tE.y};
                    float sc[6];
                    #pragma unroll
                    for (int c = 0; c < 6; ++c)
                        sc[c] = fdot2u(tw[c*3+0], hvh0,
                                fdot2u(tw[c*3+1], hvh1,
                                fdot2u(tw[c*3+2], hvh2, 0.f)));

                    const float hho = ohi ? hh[lr + 3] : hh[lr];
                    const float hvo = ohi ? hv[lr + 3] : hv[lr];
                    const float base = vv[lr] + hho + hvo;

                    float ta = fmaf(sc[0], hh[0], fmaf(sc[2], hh[2], sc[4]*hh[4]));
                    float tb = fmaf(sc[1], hh[1], fmaf(sc[3], hh[3], sc[5]*hh[5]));
                    float md = fdot2u(tE.z, hhp0, fdot2u(tE.w, hhp1,
                               fdot2u(tF.x, hhp2, 0.f)));
                    float nd = fdot2u(tF.y, hvh0, fdot2u(tF.z, hvh1,
                               fdot2u(tF.w, hvh2, 0.f)));
                    acc[lr] = ((base + ta) + (tb + md)) + nd;
                }

                // 4-lane reductions via DPP quad_perm (pure VALU, no LDS)
                float a2_[3];
                #pragma unroll
                for (int lr = 0; lr < 3; ++lr) a2_[lr] = acc[lr] * acc[lr];
                float ssl = (a2_[0] + a2_[1]) + a2_[2];
                float pq  = fmaf(e2[0], a2_[0], fmaf(e2[1], a2_[1], e2[2] * a2_[2]));
                float s1  = ssl + DPPF(ssl, QP_XOR1);
                float ssq = s1 + DPPF(s1, QP_XOR2);
                float p1  = pq + DPPF(pq, QP_XOR1);
                float px  = DPPF(p1, QP_XOR2);
                const float inv = FAST_RSQ(ssq + 1e-12f);

                const int sel = (cbr >> qq) & 1;
                const float qsel = (mya == sel) ? p1 : px;
                amp2 *= qsel * FAST_RCP(p1 + px);

                // normalize, then rebuild h_sel via static quad-broadcasts
                float an[3];
                #pragma unroll
                for (int k = 0; k < 3; ++k) an[k] = acc[k] * inv;
                #pragma unroll
                for (int k = 0; k < 3; ++k) {
                    float b0 = DPPF(an[k], QP_BC0);
                    float b1 = DPPF(an[k], QP_BC1);
                    float b2 = DPPF(an[k], QP_BC2);
                    float b3 = DPPF(an[k], QP_BC3);
                    hh[k]     = sel ? b2 : b0;
                    hh[k + 3] = sel ? b3 : b1;
                }

                // phase: tree (depth 3)
                float pA = fmaf(wq[1], hh[1], wq[0] * hh[0]);
                float pB = fmaf(wq[3], hh[3], wq[2] * hh[2]);
                float pC = fmaf(wq[5], hh[5], fmaf(wq[4], hh[4], ck));
                phi += (pA + pB) + pC;

                if (sub == 0) {
                    float* vrow = vsm + j * 768 + s * 12;
                    *reinterpret_cast<float4*>(vrow) =
                        make_float4(hh[0], hh[1], hh[2], hh[3]);
                    *reinterpret_cast<float2*>(vrow + 4) =
                        make_float2(hh[4], hh[5]);
                }
            }
        }
    }

    if (sub == 0 && valid) {
        const float amp = sqrtf(amp2);
        if (writeImag) {
            out[2 * b + 0] = amp * cosf(phi);
            out[2 * b + 1] = amp * sinf(phi);
        } else {
            out[b] = amp * cosf(phi);
        }
    }
}

extern "C" void kernel_launch(void* const* d_in, const int* in_sizes, int n_in,
                              void* d_out, int out_size, void* d_ws, size_t ws_size,
                              hipStream_t stream) {
    const float* Mh = (const float*)d_in[0];
    const float* Mv = (const float*)d_in[1];
    const float* Vp = (const float*)d_in[2];
    const float* Tp = (const float*)d_in[3];
    const float* Wp = (const float*)d_in[4];
    const float* Cp = (const float*)d_in[5];
    const float* Ep = (const float*)d_in[6];
    const int*   X  = (const int*)d_in[7];
    float* out = (float*)d_out;

    const int Bn = in_sizes[7] / NQ;                 // 32768
    const int writeImag = (out_size >= 2 * Bn) ? 1 : 0;
    const int grid = (Bn + SPB - 1) / SPB;           // 512 blocks of 256 threads

    mps_rnn14<<<grid, BT, 0, stream>>>(Mh, Mv, Vp, Tp, Wp, Cp, Ep, X, out,
                                       Bn, writeImag);
}